// Round 12
// baseline (294.393 us; speedup 1.0000x reference)
//
#include <hip/hip_runtime.h>

#define NN 8192
#define TT 60
#define DF 6
#define HH 64
#define GG 256   // 4*H
#define RS 132   // payload width: [0..63] u*last, [64..127] w*last, [128] u, [129] w
#define CH 32    // ranks per chunk
#define NB 256   // chunks / tail grid

typedef _Float16 half8 __attribute__((ext_vector_type(8)));
typedef float f32x4 __attribute__((ext_vector_type(4)));
#define MFMA16(a, b, c) __builtin_amdgcn_mfma_f32_16x16x32_f16((a), (b), (c), 0, 0, 0)

__device__ __forceinline__ float sigmoidf_(float x) {
    return __builtin_amdgcn_rcpf(1.0f + __expf(-x));
}
__device__ __forceinline__ float tanhf_(float x) {
    return __builtin_fmaf(2.0f, __builtin_amdgcn_rcpf(1.0f + __expf(-2.0f * x)), -1.0f);
}
__device__ __forceinline__ float lrelu_(float x) { return x > 0.0f ? x : 0.01f * x; }

__device__ __forceinline__ half8 ldw8(const float* __restrict__ p) {
    const float4* q = (const float4*)p;
    float4 u = q[0], v = q[1];
    half8 r;
    r[0]=(_Float16)u.x; r[1]=(_Float16)u.y; r[2]=(_Float16)u.z; r[3]=(_Float16)u.w;
    r[4]=(_Float16)v.x; r[5]=(_Float16)v.y; r[6]=(_Float16)v.z; r[7]=(_Float16)v.w;
    return r;
}

// ---------------------------------------------------------------------------
// K1: MFMA 2-layer LSTM + GAT-prep epilogue (s1/s2). Also zeroes chunkSum
// (stream-ordered before K2's atomics; d_ws is re-poisoned every launch).
// ---------------------------------------------------------------------------
#define SXW (TT * 8 + 8)

__global__ __launch_bounds__(512, 4)
void lstm_fused_kernel(const float* __restrict__ x,
                       const float* __restrict__ Wih0, const float* __restrict__ Whh0,
                       const float* __restrict__ bih0, const float* __restrict__ bhh0,
                       const float* __restrict__ Wih1, const float* __restrict__ Whh1,
                       const float* __restrict__ bih1, const float* __restrict__ bhh1,
                       const float* __restrict__ Wt, const float* __restrict__ bt,
                       const float* __restrict__ av,
                       float* __restrict__ last_out,
                       float* __restrict__ s1g, float* __restrict__ s2g,
                       float* __restrict__ chunkSum)
{
    __shared__ _Float16 sxp[16][SXW];
    __shared__ _Float16 h0buf[2][16][72];
    __shared__ _Float16 h1buf[2][16][72];
    __shared__ _Float16 zero16[8];
    __shared__ float sv1[HH], sv2[HH], sc12[2];

    const int tid  = threadIdx.x;
    const int w    = tid >> 6;
    const int grp  = w >> 2;
    const int cg   = w & 3;
    const int lane = tid & 63;
    const int quad = lane >> 4;
    const int l15  = lane & 15;
    const int hc   = cg * 16 + l15;
    const int n0   = blockIdx.x * 16;

    // zero my 66-float slice of chunkSum (512 blocks x 66 = 33792 = NB*RS)
    {
        const int base = blockIdx.x * 66;
        for (int q = tid; q < 66; q += 512) chunkSum[base + q] = 0.f;
    }

    for (int i = tid; i < 16 * SXW / 2; i += 512) ((unsigned*)sxp)[i] = 0u;
    for (int i = tid; i < 2 * 16 * 72 / 2; i += 512) ((unsigned*)h0buf)[i] = 0u;
    for (int i = tid; i < 2 * 16 * 72 / 2; i += 512) ((unsigned*)h1buf)[i] = 0u;
    if (tid < 4) ((unsigned*)zero16)[tid] = 0u;
    __syncthreads();

    for (int idx = tid; idx < 16 * TT * DF; idx += 512) {
        const int m = idx / (TT * DF);
        const int r = idx - m * (TT * DF);
        const int t = r / DF;
        const int d = r - t * DF;
        sxp[m][t * 8 + d] = (_Float16)x[(size_t)(n0 + m) * (TT * DF) + r];
    }

    if (tid < HH) {
        float a1 = 0.f, a2 = 0.f;
        #pragma unroll 8
        for (int h = 0; h < HH; h++) {
            const float wt = Wt[h * HH + tid];
            a1 += wt * av[h];
            a2 += wt * av[HH + h];
        }
        sv1[tid] = a1; sv2[tid] = a2;
    } else if (tid == 64 || tid == 65) {
        const float* ap = av + (tid - 64) * HH;
        float c = 0.f;
        #pragma unroll 8
        for (int h = 0; h < HH; h++) c += bt[h] * ap[h];
        sc12[tid - 64] = c;
    }

    half8 wA[4][2], wB[4][2];
    float bias[4];
    half8 hzero;
    #pragma unroll
    for (int j = 0; j < 8; j++) hzero[j] = (_Float16)0.f;

    if (grp == 0) {
        #pragma unroll
        for (int nt = 0; nt < 4; nt++) {
            const int g = nt * 64 + hc;
            wA[nt][0] = ldw8(Whh0 + (size_t)g * HH + quad * 8);
            wA[nt][1] = ldw8(Whh0 + (size_t)g * HH + 32 + quad * 8);
            bias[nt]  = bih0[g] + bhh0[g];
            half8 t = hzero;
            if (quad == 0) {
                #pragma unroll
                for (int j = 0; j < DF; j++) t[j] = (_Float16)Wih0[g * DF + j];
            }
            wB[nt][0] = t;
            wB[nt][1] = hzero;
        }
    } else {
        #pragma unroll
        for (int nt = 0; nt < 4; nt++) {
            const int g = nt * 64 + hc;
            wA[nt][0] = ldw8(Wih1 + (size_t)g * HH + quad * 8);
            wA[nt][1] = ldw8(Wih1 + (size_t)g * HH + 32 + quad * 8);
            wB[nt][0] = ldw8(Whh1 + (size_t)g * HH + quad * 8);
            wB[nt][1] = ldw8(Whh1 + (size_t)g * HH + 32 + quad * 8);
            bias[nt]  = bih1[g] + bhh1[g];
        }
    }

    float cs[4] = {0.f, 0.f, 0.f, 0.f};
    __syncthreads();

    for (int i = 0; i <= TT; i++) {
        const int p = i & 1;
        if (grp == 0) {
            if (i < TT) {
                const half8 a0 = *(const half8*)&h0buf[p][l15][quad * 8];
                const half8 a1 = *(const half8*)&h0buf[p][l15][32 + quad * 8];
                const _Float16* xap = (quad == 0) ? &sxp[l15][i * 8] : zero16;
                const half8 ax = *(const half8*)xap;
                f32x4 gv[4];
                #pragma unroll
                for (int nt = 0; nt < 4; nt++) {
                    f32x4 c; c[0] = bias[nt]; c[1] = bias[nt]; c[2] = bias[nt]; c[3] = bias[nt];
                    c = MFMA16(ax, wB[nt][0], c);
                    c = MFMA16(a0, wA[nt][0], c);
                    c = MFMA16(a1, wA[nt][1], c);
                    gv[nt] = c;
                }
                _Float16 (*h0w)[72] = h0buf[p ^ 1];
                #pragma unroll
                for (int reg = 0; reg < 4; reg++) {
                    const float gi = gv[0][reg], gf = gv[1][reg], gc = gv[2][reg], go = gv[3][reg];
                    const float cc = sigmoidf_(gf) * cs[reg] + sigmoidf_(gi) * tanhf_(gc);
                    cs[reg] = cc;
                    h0w[quad * 4 + reg][hc] = (_Float16)(sigmoidf_(go) * tanhf_(cc));
                }
            }
        } else {
            if (i > 0) {
                const half8 a00 = *(const half8*)&h0buf[p][l15][quad * 8];
                const half8 a01 = *(const half8*)&h0buf[p][l15][32 + quad * 8];
                const half8 a10 = *(const half8*)&h1buf[p][l15][quad * 8];
                const half8 a11 = *(const half8*)&h1buf[p][l15][32 + quad * 8];
                f32x4 gv[4];
                #pragma unroll
                for (int nt = 0; nt < 4; nt++) {
                    f32x4 c; c[0] = bias[nt]; c[1] = bias[nt]; c[2] = bias[nt]; c[3] = bias[nt];
                    c = MFMA16(a00, wA[nt][0], c);
                    c = MFMA16(a01, wA[nt][1], c);
                    c = MFMA16(a10, wB[nt][0], c);
                    c = MFMA16(a11, wB[nt][1], c);
                    gv[nt] = c;
                }
                _Float16 (*h1w)[72] = h1buf[p ^ 1];
                #pragma unroll
                for (int reg = 0; reg < 4; reg++) {
                    const float gi = gv[0][reg], gf = gv[1][reg], gc = gv[2][reg], go = gv[3][reg];
                    const float cc = sigmoidf_(gf) * cs[reg] + sigmoidf_(gi) * tanhf_(gc);
                    cs[reg] = cc;
                    const float hv = sigmoidf_(go) * tanhf_(cc);
                    h1w[quad * 4 + reg][hc] = (_Float16)hv;
                    if (i == TT) last_out[(size_t)(n0 + quad * 4 + reg) * HH + hc] = hv;
                }
            }
        }
        __syncthreads();
    }

    // epilogue: s1/s2 from final h1 (h1buf[1]; TT even)
    {
        const _Float16 (*hf)[72] = h1buf[1];
        const int r  = tid >> 5;
        const int c0 = tid & 31;
        const float h1a = (float)hf[r][c0];
        const float h1b = (float)hf[r][c0 + 32];
        float p1 = h1a * sv1[c0] + h1b * sv1[c0 + 32];
        float p2 = h1a * sv2[c0] + h1b * sv2[c0 + 32];
        #pragma unroll
        for (int off = 16; off > 0; off >>= 1) {
            p1 += __shfl_xor(p1, off);
            p2 += __shfl_xor(p2, off);
        }
        if (c0 == 0) {
            s1g[n0 + r] = p1 + sc12[0];
            s2g[n0 + r] = p2 + sc12[1];
        }
    }
}

// ---------------------------------------------------------------------------
// K2: rank + factors + ATOMIC chunk-sum scatter. Block b owns nodes
// [32b,32b+32). Each node's payload {u*last, w*last, u, w} is atomically
// added to chunkSum[rank/32] — kills the old gather kernel (scanA).
// ---------------------------------------------------------------------------
__global__ __launch_bounds__(256)
void rankscatter_kernel(const float* __restrict__ s1g, const float* __restrict__ s2g,
                        const float* __restrict__ last,
                        float* __restrict__ Z, float* __restrict__ Ai, float* __restrict__ Bi,
                        float* __restrict__ U, float* __restrict__ W,
                        int* __restrict__ iperm, float* __restrict__ sortedD,
                        float* __restrict__ chunkSum)
{
    __shared__ float sb[NN];      // 32 KB
    __shared__ float sred[256];
    __shared__ int   sRank[32];
    __shared__ float sU[32], sWw[32];
    const int tid = threadIdx.x;
    const int b   = blockIdx.x;
    const int j0  = b * 32;

    for (int idx = tid; idx < NN; idx += 256) sb[idx] = s1g[idx];
    if (tid < 32) sRank[tid] = 0;
    __syncthreads();

    float m = -1e30f;
    for (int idx = tid; idx < NN; idx += 256) m = fmaxf(m, sb[idx]);
    sred[tid] = m;
    __syncthreads();
    for (int s = 128; s > 0; s >>= 1) {
        if (tid < s) sred[tid] = fmaxf(sred[tid], sred[tid + s]);
        __syncthreads();
    }
    const float s1max = sred[0];

    if (tid < 32) {
        const int j = j0 + tid;
        const float z  = s2g[j] + s1max;
        const float mi = lrelu_(z);
        Z[j]  = z;
        Ai[j] = __expf(z - mi);
        Bi[j] = __expf(0.01f * z - mi);
        const float d = sb[j] - s1max;
        const float u = __expf(d);
        const float ww = __expf(0.01f * d);
        U[j] = u; W[j] = ww;
        sU[tid] = u; sWw[tid] = ww;
    }
    __syncthreads();
    {
        const int jl = tid & 31;
        const int part = tid >> 5;          // 0..7
        const float sj = sb[j0 + jl];
        const int jg = j0 + jl;
        int cnt = 0;
        const int k0 = part * (NN / 8);
        #pragma unroll 4
        for (int k = k0; k < k0 + NN / 8; k++) {
            const float sk = sb[k];
            cnt += (sk < sj || (sk == sj && k < jg)) ? 1 : 0;
        }
        atomicAdd(&sRank[jl], cnt);
    }
    __syncthreads();
    if (tid < 32) {
        const int r = sRank[tid];
        iperm[r] = j0 + tid;
        sortedD[r] = sb[j0 + tid] - s1max;
    }
    __syncthreads();
    // atomic payload scatter: wave wv handles nodes wv*8..wv*8+7
    const int wv = tid >> 6, lane = tid & 63;
    #pragma unroll
    for (int jj = 0; jj < 8; jj++) {
        const int jl = wv * 8 + jj;
        const int j  = j0 + jl;
        const int c  = sRank[jl] >> 5;     // chunk
        const float u = sU[jl], ww = sWw[jl];
        const float lv = last[(size_t)j * HH + lane];
        float* dst = chunkSum + (size_t)c * RS;
        atomicAdd(&dst[lane],      u * lv);
        atomicAdd(&dst[64 + lane], ww * lv);
        if (lane == 0) {
            atomicAdd(&dst[128], u);
            atomicAdd(&dst[129], ww);
        }
    }
}

// ---------------------------------------------------------------------------
// K3: PP fill. Block b = chunk b: chunk offset from 256 masked coalesced
// chunkSum loads (scanB folded in); own 32 rows' payload gathered via iperm;
// serial 32-walk writes PP rows (prefix W-group / suffix U-group).
// ---------------------------------------------------------------------------
__global__ __launch_bounds__(256)
void ppfill_kernel(const float* __restrict__ last, const float* __restrict__ U,
                   const float* __restrict__ W, const int* __restrict__ iperm,
                   const float* __restrict__ chunkSum, float* __restrict__ PP)
{
    __shared__ int   sj[CH];
    __shared__ float su[CH], sw[CH];
    __shared__ float al[CH][HH], bl[CH][HH];
    const int tid = threadIdx.x;
    const int b   = blockIdx.x;
    if (tid < CH) {
        const int j = iperm[b * CH + tid];
        sj[tid] = j; su[tid] = U[j]; sw[tid] = W[j];
    }
    __syncthreads();
    for (int idx = tid; idx < CH * HH; idx += 256) {
        const int rr = idx >> 6, c = idx & 63;
        const float lv = last[(size_t)sj[rr] * HH + c];
        al[rr][c] = su[rr] * lv;
        bl[rr][c] = sw[rr] * lv;
    }
    __syncthreads();
    if (tid < 130) {
        const int c = tid;
        const bool rev = (c < 64) || (c == 128);
        float run = 0.f;
        for (int bb = 0; bb < NB; bb++) {
            const float v = chunkSum[bb * RS + c];
            run += ((rev ? (bb > b) : (bb < b)) ? v : 0.f);
        }
        if (rev) {
            if (b == NB - 1) PP[(size_t)NN * RS + c] = 0.f;
            for (int rr = CH - 1; rr >= 0; rr--) {
                const float val = (c < 64) ? al[rr][c] : su[rr];
                run += val;
                PP[(size_t)(b * CH + rr) * RS + c] = run;
            }
        } else {
            for (int rr = 0; rr < CH; rr++) {
                PP[(size_t)(b * CH + rr) * RS + c] = run;
                run += (c < 128) ? bl[rr][c - 64] : sw[rr];
            }
            if (b == NB - 1) PP[(size_t)NN * RS + c] = run;
        }
    }
}

// ---------------------------------------------------------------------------
// K4: apply + FC head (unchanged from R11).
// ---------------------------------------------------------------------------
__global__ __launch_bounds__(256)
void applyfc_kernel(const float* __restrict__ last,
                    const float* __restrict__ Z, const float* __restrict__ Ai, const float* __restrict__ Bi,
                    const float* __restrict__ sortedD, const float* __restrict__ PP,
                    const float* __restrict__ Wfc, const float* __restrict__ bfc,
                    const float* __restrict__ Wout, const float* __restrict__ bout,
                    float* __restrict__ out)
{
    __shared__ float sdD[NN];          // 32 KB
    __shared__ float sW[HH][HH + 1];
    __shared__ float sbF[HH], saF[HH];
    const int tid = threadIdx.x;
    for (int idx = tid; idx < NN; idx += 256) sdD[idx] = sortedD[idx];
    for (int idx = tid; idx < HH * HH; idx += 256) {
        const int h = idx >> 6, d = idx & 63;
        sW[d][h] = Wfc[idx];
    }
    if (tid < HH) { sbF[tid] = bfc[tid]; saF[tid] = Wout[tid]; }
    __syncthreads();

    const int wv = tid >> 6, lane = tid & 63;
    const int i0 = blockIdx.x * 32 + wv * 8;
    float zi[8]; int lo[8], hi[8];
    #pragma unroll
    for (int q = 0; q < 8; q++) { zi[q] = Z[i0 + q]; lo[q] = 0; hi[q] = NN; }
    for (int iter = 0; iter < 13; iter++) {
        #pragma unroll
        for (int q = 0; q < 8; q++) {
            if (lo[q] < hi[q]) {
                const int mid = (lo[q] + hi[q]) >> 1;
                const float dm = sdD[mid];
                if (zi[q] + dm > 0.f) hi[q] = mid; else lo[q] = mid + 1;
            }
        }
    }
    float gv[8];
    #pragma unroll
    for (int q = 0; q < 8; q++) {
        const int i = i0 + q;
        const float* rowp = PP + (size_t)lo[q] * RS;
        const float pu  = rowp[lane];
        const float pw  = rowp[64 + lane];
        const float pud = rowp[128];
        const float pwd = rowp[129];
        const float ai = Ai[i], bi = Bi[i];
        const float numer = bi * pw + ai * pu;
        const float den   = bi * pwd + ai * pud;
        const float lv = last[(size_t)i * HH + lane];
        gv[q] = numer * __builtin_amdgcn_rcpf(den) + lv;
    }
    const float bo = bout[0];
    #pragma unroll
    for (int q = 0; q < 8; q++) {
        float acc = sbF[lane];
        #pragma unroll
        for (int d = 0; d < HH; d++) acc += __shfl(gv[q], d) * sW[d][lane];
        float prod = lrelu_(acc) * saF[lane];
        #pragma unroll
        for (int off = 32; off > 0; off >>= 1) prod += __shfl_xor(prod, off);
        if (lane == 0) out[i0 + q] = prod + bo;
    }
}

extern "C" void kernel_launch(void* const* d_in, const int* in_sizes, int n_in,
                              void* d_out, int out_size, void* d_ws, size_t ws_size,
                              hipStream_t stream)
{
    (void)in_sizes; (void)n_in; (void)out_size; (void)ws_size;
    const float* x    = (const float*)d_in[0];
    const float* Wih0 = (const float*)d_in[1];
    const float* Whh0 = (const float*)d_in[2];
    const float* bih0 = (const float*)d_in[3];
    const float* bhh0 = (const float*)d_in[4];
    const float* Wih1 = (const float*)d_in[5];
    const float* Whh1 = (const float*)d_in[6];
    const float* bih1 = (const float*)d_in[7];
    const float* bhh1 = (const float*)d_in[8];
    const float* Wt   = (const float*)d_in[9];
    const float* bt   = (const float*)d_in[10];
    const float* a    = (const float*)d_in[11];
    const float* Wfc  = (const float*)d_in[12];
    const float* bfc  = (const float*)d_in[13];
    const float* Wout = (const float*)d_in[14];
    const float* bout = (const float*)d_in[15];
    float* out = (float*)d_out;

    float* ws       = (float*)d_ws;
    float* last     = ws;                           // N*H
    float* s1g      = last + (size_t)NN*HH;         // N
    float* s2g      = s1g + NN;                     // N
    float* Z        = s2g + NN;                     // N
    float* Ai       = Z + NN;                       // N
    float* Bi       = Ai + NN;                      // N
    float* U        = Bi + NN;                      // N
    float* W        = U + NN;                       // N
    float* sortedD  = W + NN;                       // N
    int*   iperm    = (int*)(sortedD + NN);         // N ints
    float* chunkSum = (float*)(iperm + NN);         // NB*RS
    float* PP       = chunkSum + NB*RS;             // (N+1)*RS

    lstm_fused_kernel<<<dim3(NN / 16), dim3(512), 0, stream>>>(
        x, Wih0, Whh0, bih0, bhh0, Wih1, Whh1, bih1, bhh1,
        Wt, bt, a, last, s1g, s2g, chunkSum);
    rankscatter_kernel<<<dim3(NB), dim3(256), 0, stream>>>(
        s1g, s2g, last, Z, Ai, Bi, U, W, iperm, sortedD, chunkSum);
    ppfill_kernel<<<dim3(NB), dim3(256), 0, stream>>>(
        last, U, W, iperm, chunkSum, PP);
    applyfc_kernel<<<dim3(NB), dim3(256), 0, stream>>>(
        last, Z, Ai, Bi, sortedD, PP, Wfc, bfc, Wout, bout, out);
}

// Round 13
// 293.862 us; speedup vs baseline: 1.0018x; 1.0018x over previous
//
#include <hip/hip_runtime.h>

#define NN 8192
#define TT 60
#define DF 6
#define HH 64
#define GG 256   // 4*H
#define RS 132   // payload width: [0..63] u*last, [64..127] w*last, [128] u, [129] w
#define CH 32    // ranks per chunk/block
#define NB 256   // chunks

typedef _Float16 half8 __attribute__((ext_vector_type(8)));
typedef float f32x4 __attribute__((ext_vector_type(4)));
#define MFMA16(a, b, c) __builtin_amdgcn_mfma_f32_16x16x32_f16((a), (b), (c), 0, 0, 0)

__device__ __forceinline__ float sigmoidf_(float x) {
    return __builtin_amdgcn_rcpf(1.0f + __expf(-x));
}
__device__ __forceinline__ float tanhf_(float x) {
    return __builtin_fmaf(2.0f, __builtin_amdgcn_rcpf(1.0f + __expf(-2.0f * x)), -1.0f);
}
__device__ __forceinline__ float lrelu_(float x) { return x > 0.0f ? x : 0.01f * x; }

__device__ __forceinline__ half8 ldw8(const float* __restrict__ p) {
    const float4* q = (const float4*)p;
    float4 u = q[0], v = q[1];
    half8 r;
    r[0]=(_Float16)u.x; r[1]=(_Float16)u.y; r[2]=(_Float16)u.z; r[3]=(_Float16)u.w;
    r[4]=(_Float16)v.x; r[5]=(_Float16)v.y; r[6]=(_Float16)v.z; r[7]=(_Float16)v.w;
    return r;
}

// ---------------------------------------------------------------------------
// K1: MFMA 2-layer LSTM + GAT-prep epilogue (s1/s2) — R11 verbatim.
// ---------------------------------------------------------------------------
#define SXW (TT * 8 + 8)

__global__ __launch_bounds__(512, 4)
void lstm_fused_kernel(const float* __restrict__ x,
                       const float* __restrict__ Wih0, const float* __restrict__ Whh0,
                       const float* __restrict__ bih0, const float* __restrict__ bhh0,
                       const float* __restrict__ Wih1, const float* __restrict__ Whh1,
                       const float* __restrict__ bih1, const float* __restrict__ bhh1,
                       const float* __restrict__ Wt, const float* __restrict__ bt,
                       const float* __restrict__ av,
                       float* __restrict__ last_out,
                       float* __restrict__ s1g, float* __restrict__ s2g)
{
    __shared__ _Float16 sxp[16][SXW];
    __shared__ _Float16 h0buf[2][16][72];
    __shared__ _Float16 h1buf[2][16][72];
    __shared__ _Float16 zero16[8];
    __shared__ float sv1[HH], sv2[HH], sc12[2];

    const int tid  = threadIdx.x;
    const int w    = tid >> 6;
    const int grp  = w >> 2;
    const int cg   = w & 3;
    const int lane = tid & 63;
    const int quad = lane >> 4;
    const int l15  = lane & 15;
    const int hc   = cg * 16 + l15;
    const int n0   = blockIdx.x * 16;

    for (int i = tid; i < 16 * SXW / 2; i += 512) ((unsigned*)sxp)[i] = 0u;
    for (int i = tid; i < 2 * 16 * 72 / 2; i += 512) ((unsigned*)h0buf)[i] = 0u;
    for (int i = tid; i < 2 * 16 * 72 / 2; i += 512) ((unsigned*)h1buf)[i] = 0u;
    if (tid < 4) ((unsigned*)zero16)[tid] = 0u;
    __syncthreads();

    for (int idx = tid; idx < 16 * TT * DF; idx += 512) {
        const int m = idx / (TT * DF);
        const int r = idx - m * (TT * DF);
        const int t = r / DF;
        const int d = r - t * DF;
        sxp[m][t * 8 + d] = (_Float16)x[(size_t)(n0 + m) * (TT * DF) + r];
    }

    if (tid < HH) {
        float a1 = 0.f, a2 = 0.f;
        #pragma unroll 8
        for (int h = 0; h < HH; h++) {
            const float wt = Wt[h * HH + tid];
            a1 += wt * av[h];
            a2 += wt * av[HH + h];
        }
        sv1[tid] = a1; sv2[tid] = a2;
    } else if (tid == 64 || tid == 65) {
        const float* ap = av + (tid - 64) * HH;
        float c = 0.f;
        #pragma unroll 8
        for (int h = 0; h < HH; h++) c += bt[h] * ap[h];
        sc12[tid - 64] = c;
    }

    half8 wA[4][2], wB[4][2];
    float bias[4];
    half8 hzero;
    #pragma unroll
    for (int j = 0; j < 8; j++) hzero[j] = (_Float16)0.f;

    if (grp == 0) {
        #pragma unroll
        for (int nt = 0; nt < 4; nt++) {
            const int g = nt * 64 + hc;
            wA[nt][0] = ldw8(Whh0 + (size_t)g * HH + quad * 8);
            wA[nt][1] = ldw8(Whh0 + (size_t)g * HH + 32 + quad * 8);
            bias[nt]  = bih0[g] + bhh0[g];
            half8 t = hzero;
            if (quad == 0) {
                #pragma unroll
                for (int j = 0; j < DF; j++) t[j] = (_Float16)Wih0[g * DF + j];
            }
            wB[nt][0] = t;
            wB[nt][1] = hzero;
        }
    } else {
        #pragma unroll
        for (int nt = 0; nt < 4; nt++) {
            const int g = nt * 64 + hc;
            wA[nt][0] = ldw8(Wih1 + (size_t)g * HH + quad * 8);
            wA[nt][1] = ldw8(Wih1 + (size_t)g * HH + 32 + quad * 8);
            wB[nt][0] = ldw8(Whh1 + (size_t)g * HH + quad * 8);
            wB[nt][1] = ldw8(Whh1 + (size_t)g * HH + 32 + quad * 8);
            bias[nt]  = bih1[g] + bhh1[g];
        }
    }

    float cs[4] = {0.f, 0.f, 0.f, 0.f};
    __syncthreads();

    for (int i = 0; i <= TT; i++) {
        const int p = i & 1;
        if (grp == 0) {
            if (i < TT) {
                const half8 a0 = *(const half8*)&h0buf[p][l15][quad * 8];
                const half8 a1 = *(const half8*)&h0buf[p][l15][32 + quad * 8];
                const _Float16* xap = (quad == 0) ? &sxp[l15][i * 8] : zero16;
                const half8 ax = *(const half8*)xap;
                f32x4 gv[4];
                #pragma unroll
                for (int nt = 0; nt < 4; nt++) {
                    f32x4 c; c[0] = bias[nt]; c[1] = bias[nt]; c[2] = bias[nt]; c[3] = bias[nt];
                    c = MFMA16(ax, wB[nt][0], c);
                    c = MFMA16(a0, wA[nt][0], c);
                    c = MFMA16(a1, wA[nt][1], c);
                    gv[nt] = c;
                }
                _Float16 (*h0w)[72] = h0buf[p ^ 1];
                #pragma unroll
                for (int reg = 0; reg < 4; reg++) {
                    const float gi = gv[0][reg], gf = gv[1][reg], gc = gv[2][reg], go = gv[3][reg];
                    const float cc = sigmoidf_(gf) * cs[reg] + sigmoidf_(gi) * tanhf_(gc);
                    cs[reg] = cc;
                    h0w[quad * 4 + reg][hc] = (_Float16)(sigmoidf_(go) * tanhf_(cc));
                }
            }
        } else {
            if (i > 0) {
                const half8 a00 = *(const half8*)&h0buf[p][l15][quad * 8];
                const half8 a01 = *(const half8*)&h0buf[p][l15][32 + quad * 8];
                const half8 a10 = *(const half8*)&h1buf[p][l15][quad * 8];
                const half8 a11 = *(const half8*)&h1buf[p][l15][32 + quad * 8];
                f32x4 gv[4];
                #pragma unroll
                for (int nt = 0; nt < 4; nt++) {
                    f32x4 c; c[0] = bias[nt]; c[1] = bias[nt]; c[2] = bias[nt]; c[3] = bias[nt];
                    c = MFMA16(a00, wA[nt][0], c);
                    c = MFMA16(a01, wA[nt][1], c);
                    c = MFMA16(a10, wB[nt][0], c);
                    c = MFMA16(a11, wB[nt][1], c);
                    gv[nt] = c;
                }
                _Float16 (*h1w)[72] = h1buf[p ^ 1];
                #pragma unroll
                for (int reg = 0; reg < 4; reg++) {
                    const float gi = gv[0][reg], gf = gv[1][reg], gc = gv[2][reg], go = gv[3][reg];
                    const float cc = sigmoidf_(gf) * cs[reg] + sigmoidf_(gi) * tanhf_(gc);
                    cs[reg] = cc;
                    const float hv = sigmoidf_(go) * tanhf_(cc);
                    h1w[quad * 4 + reg][hc] = (_Float16)hv;
                    if (i == TT) last_out[(size_t)(n0 + quad * 4 + reg) * HH + hc] = hv;
                }
            }
        }
        __syncthreads();
    }

    // epilogue: s1/s2 from final h1 (h1buf[1]; TT even)
    {
        const _Float16 (*hf)[72] = h1buf[1];
        const int r  = tid >> 5;
        const int c0 = tid & 31;
        const float h1a = (float)hf[r][c0];
        const float h1b = (float)hf[r][c0 + 32];
        float p1 = h1a * sv1[c0] + h1b * sv1[c0 + 32];
        float p2 = h1a * sv2[c0] + h1b * sv2[c0 + 32];
        #pragma unroll
        for (int off = 16; off > 0; off >>= 1) {
            p1 += __shfl_xor(p1, off);
            p2 += __shfl_xor(p2, off);
        }
        if (c0 == 0) {
            s1g[n0 + r] = p1 + sc12[0];
            s2g[n0 + r] = p2 + sc12[1];
        }
    }
}

// ---------------------------------------------------------------------------
// K2: rank + factors (R11 verbatim).
// ---------------------------------------------------------------------------
__global__ __launch_bounds__(256)
void rankfac_kernel(const float* __restrict__ s1g, const float* __restrict__ s2g,
                    float* __restrict__ Z, float* __restrict__ Ai, float* __restrict__ Bi,
                    float* __restrict__ U, float* __restrict__ W,
                    int* __restrict__ iperm, float* __restrict__ sortedD)
{
    __shared__ float sb[NN];      // 32 KB
    __shared__ float sred[256];
    __shared__ int   sRank[32];
    const int tid = threadIdx.x;
    const int b   = blockIdx.x;
    const int j0  = b * 32;

    for (int idx = tid; idx < NN; idx += 256) sb[idx] = s1g[idx];
    if (tid < 32) sRank[tid] = 0;
    __syncthreads();

    float m = -1e30f;
    for (int idx = tid; idx < NN; idx += 256) m = fmaxf(m, sb[idx]);
    sred[tid] = m;
    __syncthreads();
    for (int s = 128; s > 0; s >>= 1) {
        if (tid < s) sred[tid] = fmaxf(sred[tid], sred[tid + s]);
        __syncthreads();
    }
    const float s1max = sred[0];

    if (tid < 32) {
        const int j = j0 + tid;
        const float z  = s2g[j] + s1max;
        const float mi = lrelu_(z);
        Z[j]  = z;
        Ai[j] = __expf(z - mi);
        Bi[j] = __expf(0.01f * z - mi);
        const float d = sb[j] - s1max;
        U[j] = __expf(d);
        W[j] = __expf(0.01f * d);
    }
    {
        const int jl = tid & 31;
        const int part = tid >> 5;          // 0..7
        const float sj = sb[j0 + jl];
        const int jg = j0 + jl;
        int cnt = 0;
        const int k0 = part * (NN / 8);
        #pragma unroll 4
        for (int k = k0; k < k0 + NN / 8; k++) {
            const float sk = sb[k];
            cnt += (sk < sj || (sk == sj && k < jg)) ? 1 : 0;
        }
        atomicAdd(&sRank[jl], cnt);
    }
    __syncthreads();
    if (tid < 32) {
        const int r = sRank[tid];
        iperm[r] = j0 + tid;
        sortedD[r] = sb[j0 + tid] - s1max;
    }
}

// ---------------------------------------------------------------------------
// K3: chunk column sums via iperm gather (R11 verbatim, full decls).
// ---------------------------------------------------------------------------
__global__ __launch_bounds__(256)
void scanA_kernel(const float* __restrict__ last, const float* __restrict__ U,
                  const float* __restrict__ W, const int* __restrict__ iperm,
                  float* __restrict__ chunkSum)
{
    __shared__ int   sj[CH];
    __shared__ float su[CH], sw[CH];
    __shared__ float al[CH][HH], bl[CH][HH];
    const int tid = threadIdx.x;
    const int b   = blockIdx.x;
    if (tid < CH) {
        const int j = iperm[b * CH + tid];
        sj[tid] = j; su[tid] = U[j]; sw[tid] = W[j];
    }
    __syncthreads();
    for (int idx = tid; idx < CH * HH; idx += 256) {
        const int rr = idx >> 6, c = idx & 63;
        const float lv = last[(size_t)sj[rr] * HH + c];
        al[rr][c] = su[rr] * lv;
        bl[rr][c] = sw[rr] * lv;
    }
    __syncthreads();
    if (tid < 130) {
        const int c = tid;
        float s = 0.f;
        if (c < 64) {
            for (int rr = 0; rr < CH; rr++) s += al[rr][c];
        } else if (c < 128) {
            for (int rr = 0; rr < CH; rr++) s += bl[rr][c - 64];
        } else if (c == 128) {
            for (int rr = 0; rr < CH; rr++) s += su[rr];
        } else {
            for (int rr = 0; rr < CH; rr++) s += sw[rr];
        }
        chunkSum[b * RS + c] = s;
    }
}

// ---------------------------------------------------------------------------
// K4: PP fill with scanB folded in: chunk offset from 256 independent masked
// coalesced chunkSum loads, then the 32-row serial walk (prefix W / suffix U).
// ---------------------------------------------------------------------------
__global__ __launch_bounds__(256)
void scanC_kernel(const float* __restrict__ last, const float* __restrict__ U,
                  const float* __restrict__ W, const int* __restrict__ iperm,
                  const float* __restrict__ chunkSum, float* __restrict__ PP)
{
    __shared__ int   sj[CH];
    __shared__ float su[CH], sw[CH];
    __shared__ float al[CH][HH], bl[CH][HH];
    const int tid = threadIdx.x;
    const int b   = blockIdx.x;
    if (tid < CH) {
        const int j = iperm[b * CH + tid];
        sj[tid] = j; su[tid] = U[j]; sw[tid] = W[j];
    }
    __syncthreads();
    for (int idx = tid; idx < CH * HH; idx += 256) {
        const int rr = idx >> 6, c = idx & 63;
        const float lv = last[(size_t)sj[rr] * HH + c];
        al[rr][c] = su[rr] * lv;
        bl[rr][c] = sw[rr] * lv;
    }
    __syncthreads();
    if (tid < 130) {
        const int c = tid;
        const bool rev = (c < 64) || (c == 128);
        float run = 0.f;
        for (int bb = 0; bb < NB; bb++) {
            const float v = chunkSum[bb * RS + c];
            run += ((rev ? (bb > b) : (bb < b)) ? v : 0.f);
        }
        if (rev) {
            if (b == NB - 1) PP[(size_t)NN * RS + c] = 0.f;
            for (int rr = CH - 1; rr >= 0; rr--) {
                const float val = (c < 64) ? al[rr][c] : su[rr];
                run += val;
                PP[(size_t)(b * CH + rr) * RS + c] = run;
            }
        } else {
            for (int rr = 0; rr < CH; rr++) {
                PP[(size_t)(b * CH + rr) * RS + c] = run;
                run += (c < 128) ? bl[rr][c - 64] : sw[rr];
            }
            if (b == NB - 1) PP[(size_t)NN * RS + c] = run;
        }
    }
}

// ---------------------------------------------------------------------------
// K5: apply + FC head (R11 verbatim).
// ---------------------------------------------------------------------------
__global__ __launch_bounds__(256)
void applyfc_kernel(const float* __restrict__ last,
                    const float* __restrict__ Z, const float* __restrict__ Ai, const float* __restrict__ Bi,
                    const float* __restrict__ sortedD, const float* __restrict__ PP,
                    const float* __restrict__ Wfc, const float* __restrict__ bfc,
                    const float* __restrict__ Wout, const float* __restrict__ bout,
                    float* __restrict__ out)
{
    __shared__ float sdD[NN];          // 32 KB
    __shared__ float sW[HH][HH + 1];
    __shared__ float sbF[HH], saF[HH];
    const int tid = threadIdx.x;
    for (int idx = tid; idx < NN; idx += 256) sdD[idx] = sortedD[idx];
    for (int idx = tid; idx < HH * HH; idx += 256) {
        const int h = idx >> 6, d = idx & 63;
        sW[d][h] = Wfc[idx];
    }
    if (tid < HH) { sbF[tid] = bfc[tid]; saF[tid] = Wout[tid]; }
    __syncthreads();

    const int wv = tid >> 6, lane = tid & 63;
    const int i0 = blockIdx.x * 32 + wv * 8;
    float zi[8]; int lo[8], hi[8];
    #pragma unroll
    for (int q = 0; q < 8; q++) { zi[q] = Z[i0 + q]; lo[q] = 0; hi[q] = NN; }
    for (int iter = 0; iter < 13; iter++) {
        #pragma unroll
        for (int q = 0; q < 8; q++) {
            if (lo[q] < hi[q]) {
                const int mid = (lo[q] + hi[q]) >> 1;
                const float dm = sdD[mid];
                if (zi[q] + dm > 0.f) hi[q] = mid; else lo[q] = mid + 1;
            }
        }
    }
    float gv[8];
    #pragma unroll
    for (int q = 0; q < 8; q++) {
        const int i = i0 + q;
        const float* rowp = PP + (size_t)lo[q] * RS;
        const float pu  = rowp[lane];
        const float pw  = rowp[64 + lane];
        const float pud = rowp[128];
        const float pwd = rowp[129];
        const float ai = Ai[i], bi = Bi[i];
        const float numer = bi * pw + ai * pu;
        const float den   = bi * pwd + ai * pud;
        const float lv = last[(size_t)i * HH + lane];
        gv[q] = numer * __builtin_amdgcn_rcpf(den) + lv;
    }
    const float bo = bout[0];
    #pragma unroll
    for (int q = 0; q < 8; q++) {
        float acc = sbF[lane];
        #pragma unroll
        for (int d = 0; d < HH; d++) acc += __shfl(gv[q], d) * sW[d][lane];
        float prod = lrelu_(acc) * saF[lane];
        #pragma unroll
        for (int off = 32; off > 0; off >>= 1) prod += __shfl_xor(prod, off);
        if (lane == 0) out[i0 + q] = prod + bo;
    }
}

extern "C" void kernel_launch(void* const* d_in, const int* in_sizes, int n_in,
                              void* d_out, int out_size, void* d_ws, size_t ws_size,
                              hipStream_t stream)
{
    (void)in_sizes; (void)n_in; (void)out_size; (void)ws_size;
    const float* x    = (const float*)d_in[0];
    const float* Wih0 = (const float*)d_in[1];
    const float* Whh0 = (const float*)d_in[2];
    const float* bih0 = (const float*)d_in[3];
    const float* bhh0 = (const float*)d_in[4];
    const float* Wih1 = (const float*)d_in[5];
    const float* Whh1 = (const float*)d_in[6];
    const float* bih1 = (const float*)d_in[7];
    const float* bhh1 = (const float*)d_in[8];
    const float* Wt   = (const float*)d_in[9];
    const float* bt   = (const float*)d_in[10];
    const float* a    = (const float*)d_in[11];
    const float* Wfc  = (const float*)d_in[12];
    const float* bfc  = (const float*)d_in[13];
    const float* Wout = (const float*)d_in[14];
    const float* bout = (const float*)d_in[15];
    float* out = (float*)d_out;

    float* ws       = (float*)d_ws;
    float* last     = ws;                           // N*H
    float* s1g      = last + (size_t)NN*HH;         // N
    float* s2g      = s1g + NN;                     // N
    float* Z        = s2g + NN;                     // N
    float* Ai       = Z + NN;                       // N
    float* Bi       = Ai + NN;                      // N
    float* U        = Bi + NN;                      // N
    float* W        = U + NN;                       // N
    float* sortedD  = W + NN;                       // N
    int*   iperm    = (int*)(sortedD + NN);         // N ints
    float* chunkSum = (float*)(iperm + NN);         // NB*RS
    float* PP       = chunkSum + NB*RS;             // (N+1)*RS

    lstm_fused_kernel<<<dim3(NN / 16), dim3(512), 0, stream>>>(
        x, Wih0, Whh0, bih0, bhh0, Wih1, Whh1, bih1, bhh1,
        Wt, bt, a, last, s1g, s2g);
    rankfac_kernel<<<dim3(NB), dim3(256), 0, stream>>>(
        s1g, s2g, Z, Ai, Bi, U, W, iperm, sortedD);
    scanA_kernel<<<dim3(NB), dim3(256), 0, stream>>>(last, U, W, iperm, chunkSum);
    scanC_kernel<<<dim3(NB), dim3(256), 0, stream>>>(last, U, W, iperm, chunkSum, PP);
    applyfc_kernel<<<dim3(NB), dim3(256), 0, stream>>>(
        last, Z, Ai, Bi, sortedD, PP, Wfc, bfc, Wout, bout, out);
}

// Round 14
// 260.809 us; speedup vs baseline: 1.1288x; 1.1267x over previous
//
#include <hip/hip_runtime.h>

#define NN 8192
#define TT 60
#define DF 6
#define HH 64
#define GG 256   // 4*H
#define RS 132   // payload width: [0..63] u*last, [64..127] w*last, [128] u, [129] w
#define CH 32    // ranks per chunk/block
#define NB 256   // chunks

typedef _Float16 half8 __attribute__((ext_vector_type(8)));
typedef float f32x4 __attribute__((ext_vector_type(4)));
#define MFMA16(a, b, c) __builtin_amdgcn_mfma_f32_16x16x32_f16((a), (b), (c), 0, 0, 0)

__device__ __forceinline__ float sigmoidf_(float x) {
    return __builtin_amdgcn_rcpf(1.0f + __expf(-x));
}
__device__ __forceinline__ float tanhf_(float x) {
    return __builtin_fmaf(2.0f, __builtin_amdgcn_rcpf(1.0f + __expf(-2.0f * x)), -1.0f);
}
__device__ __forceinline__ float lrelu_(float x) { return x > 0.0f ? x : 0.01f * x; }

__device__ __forceinline__ half8 ldw8(const float* __restrict__ p) {
    const float4* q = (const float4*)p;
    float4 u = q[0], v = q[1];
    half8 r;
    r[0]=(_Float16)u.x; r[1]=(_Float16)u.y; r[2]=(_Float16)u.z; r[3]=(_Float16)u.w;
    r[4]=(_Float16)v.x; r[5]=(_Float16)v.y; r[6]=(_Float16)v.z; r[7]=(_Float16)v.w;
    return r;
}

// ---------------------------------------------------------------------------
// K1: MFMA 2-layer LSTM + GAT-prep epilogue (s1/s2).
// ---------------------------------------------------------------------------
#define SXW (TT * 8 + 8)

__global__ __launch_bounds__(512, 4)
void lstm_fused_kernel(const float* __restrict__ x,
                       const float* __restrict__ Wih0, const float* __restrict__ Whh0,
                       const float* __restrict__ bih0, const float* __restrict__ bhh0,
                       const float* __restrict__ Wih1, const float* __restrict__ Whh1,
                       const float* __restrict__ bih1, const float* __restrict__ bhh1,
                       const float* __restrict__ Wt, const float* __restrict__ bt,
                       const float* __restrict__ av,
                       float* __restrict__ last_out,
                       float* __restrict__ s1g, float* __restrict__ s2g)
{
    __shared__ _Float16 sxp[16][SXW];
    __shared__ _Float16 h0buf[2][16][72];
    __shared__ _Float16 h1buf[2][16][72];
    __shared__ _Float16 zero16[8];
    __shared__ float sv1[HH], sv2[HH], sc12[2];

    const int tid  = threadIdx.x;
    const int w    = tid >> 6;
    const int grp  = w >> 2;
    const int cg   = w & 3;
    const int lane = tid & 63;
    const int quad = lane >> 4;
    const int l15  = lane & 15;
    const int hc   = cg * 16 + l15;
    const int n0   = blockIdx.x * 16;

    for (int i = tid; i < 16 * SXW / 2; i += 512) ((unsigned*)sxp)[i] = 0u;
    for (int i = tid; i < 2 * 16 * 72 / 2; i += 512) ((unsigned*)h0buf)[i] = 0u;
    for (int i = tid; i < 2 * 16 * 72 / 2; i += 512) ((unsigned*)h1buf)[i] = 0u;
    if (tid < 4) ((unsigned*)zero16)[tid] = 0u;
    __syncthreads();

    for (int idx = tid; idx < 16 * TT * DF; idx += 512) {
        const int m = idx / (TT * DF);
        const int r = idx - m * (TT * DF);
        const int t = r / DF;
        const int d = r - t * DF;
        sxp[m][t * 8 + d] = (_Float16)x[(size_t)(n0 + m) * (TT * DF) + r];
    }

    if (tid < HH) {
        float a1 = 0.f, a2 = 0.f;
        #pragma unroll 8
        for (int h = 0; h < HH; h++) {
            const float wt = Wt[h * HH + tid];
            a1 += wt * av[h];
            a2 += wt * av[HH + h];
        }
        sv1[tid] = a1; sv2[tid] = a2;
    } else if (tid == 64 || tid == 65) {
        const float* ap = av + (tid - 64) * HH;
        float c = 0.f;
        #pragma unroll 8
        for (int h = 0; h < HH; h++) c += bt[h] * ap[h];
        sc12[tid - 64] = c;
    }

    half8 wA[4][2], wB[4][2];
    float bias[4];
    half8 hzero;
    #pragma unroll
    for (int j = 0; j < 8; j++) hzero[j] = (_Float16)0.f;

    if (grp == 0) {
        #pragma unroll
        for (int nt = 0; nt < 4; nt++) {
            const int g = nt * 64 + hc;
            wA[nt][0] = ldw8(Whh0 + (size_t)g * HH + quad * 8);
            wA[nt][1] = ldw8(Whh0 + (size_t)g * HH + 32 + quad * 8);
            bias[nt]  = bih0[g] + bhh0[g];
            half8 t = hzero;
            if (quad == 0) {
                #pragma unroll
                for (int j = 0; j < DF; j++) t[j] = (_Float16)Wih0[g * DF + j];
            }
            wB[nt][0] = t;
            wB[nt][1] = hzero;
        }
    } else {
        #pragma unroll
        for (int nt = 0; nt < 4; nt++) {
            const int g = nt * 64 + hc;
            wA[nt][0] = ldw8(Wih1 + (size_t)g * HH + quad * 8);
            wA[nt][1] = ldw8(Wih1 + (size_t)g * HH + 32 + quad * 8);
            wB[nt][0] = ldw8(Whh1 + (size_t)g * HH + quad * 8);
            wB[nt][1] = ldw8(Whh1 + (size_t)g * HH + 32 + quad * 8);
            bias[nt]  = bih1[g] + bhh1[g];
        }
    }

    float cs[4] = {0.f, 0.f, 0.f, 0.f};
    __syncthreads();

    for (int i = 0; i <= TT; i++) {
        const int p = i & 1;
        if (grp == 0) {
            if (i < TT) {
                const half8 a0 = *(const half8*)&h0buf[p][l15][quad * 8];
                const half8 a1 = *(const half8*)&h0buf[p][l15][32 + quad * 8];
                const _Float16* xap = (quad == 0) ? &sxp[l15][i * 8] : zero16;
                const half8 ax = *(const half8*)xap;
                f32x4 gv[4];
                #pragma unroll
                for (int nt = 0; nt < 4; nt++) {
                    f32x4 c; c[0] = bias[nt]; c[1] = bias[nt]; c[2] = bias[nt]; c[3] = bias[nt];
                    c = MFMA16(ax, wB[nt][0], c);
                    c = MFMA16(a0, wA[nt][0], c);
                    c = MFMA16(a1, wA[nt][1], c);
                    gv[nt] = c;
                }
                _Float16 (*h0w)[72] = h0buf[p ^ 1];
                #pragma unroll
                for (int reg = 0; reg < 4; reg++) {
                    const float gi = gv[0][reg], gf = gv[1][reg], gc = gv[2][reg], go = gv[3][reg];
                    const float cc = sigmoidf_(gf) * cs[reg] + sigmoidf_(gi) * tanhf_(gc);
                    cs[reg] = cc;
                    h0w[quad * 4 + reg][hc] = (_Float16)(sigmoidf_(go) * tanhf_(cc));
                }
            }
        } else {
            if (i > 0) {
                const half8 a00 = *(const half8*)&h0buf[p][l15][quad * 8];
                const half8 a01 = *(const half8*)&h0buf[p][l15][32 + quad * 8];
                const half8 a10 = *(const half8*)&h1buf[p][l15][quad * 8];
                const half8 a11 = *(const half8*)&h1buf[p][l15][32 + quad * 8];
                f32x4 gv[4];
                #pragma unroll
                for (int nt = 0; nt < 4; nt++) {
                    f32x4 c; c[0] = bias[nt]; c[1] = bias[nt]; c[2] = bias[nt]; c[3] = bias[nt];
                    c = MFMA16(a00, wA[nt][0], c);
                    c = MFMA16(a01, wA[nt][1], c);
                    c = MFMA16(a10, wB[nt][0], c);
                    c = MFMA16(a11, wB[nt][1], c);
                    gv[nt] = c;
                }
                _Float16 (*h1w)[72] = h1buf[p ^ 1];
                #pragma unroll
                for (int reg = 0; reg < 4; reg++) {
                    const float gi = gv[0][reg], gf = gv[1][reg], gc = gv[2][reg], go = gv[3][reg];
                    const float cc = sigmoidf_(gf) * cs[reg] + sigmoidf_(gi) * tanhf_(gc);
                    cs[reg] = cc;
                    const float hv = sigmoidf_(go) * tanhf_(cc);
                    h1w[quad * 4 + reg][hc] = (_Float16)hv;
                    if (i == TT) last_out[(size_t)(n0 + quad * 4 + reg) * HH + hc] = hv;
                }
            }
        }
        __syncthreads();
    }

    // epilogue: s1/s2 from final h1 (h1buf[1]; TT even)
    {
        const _Float16 (*hf)[72] = h1buf[1];
        const int r  = tid >> 5;
        const int c0 = tid & 31;
        const float h1a = (float)hf[r][c0];
        const float h1b = (float)hf[r][c0 + 32];
        float p1 = h1a * sv1[c0] + h1b * sv1[c0 + 32];
        float p2 = h1a * sv2[c0] + h1b * sv2[c0 + 32];
        #pragma unroll
        for (int off = 16; off > 0; off >>= 1) {
            p1 += __shfl_xor(p1, off);
            p2 += __shfl_xor(p2, off);
        }
        if (c0 == 0) {
            s1g[n0 + r] = p1 + sc12[0];
            s2g[n0 + r] = p2 + sc12[1];
        }
    }
}

// ---------------------------------------------------------------------------
// K2: rank + factors. Block b owns nodes [32b,32b+32).
// ---------------------------------------------------------------------------
__global__ __launch_bounds__(256)
void rankfac_kernel(const float* __restrict__ s1g, const float* __restrict__ s2g,
                    float* __restrict__ Z, float* __restrict__ Ai, float* __restrict__ Bi,
                    float* __restrict__ U, float* __restrict__ W,
                    int* __restrict__ iperm, float* __restrict__ sortedD)
{
    __shared__ float sb[NN];      // 32 KB
    __shared__ float sred[256];
    __shared__ int   sRank[32];
    const int tid = threadIdx.x;
    const int b   = blockIdx.x;
    const int j0  = b * 32;

    for (int idx = tid; idx < NN; idx += 256) sb[idx] = s1g[idx];
    if (tid < 32) sRank[tid] = 0;
    __syncthreads();

    float m = -1e30f;
    for (int idx = tid; idx < NN; idx += 256) m = fmaxf(m, sb[idx]);
    sred[tid] = m;
    __syncthreads();
    for (int s = 128; s > 0; s >>= 1) {
        if (tid < s) sred[tid] = fmaxf(sred[tid], sred[tid + s]);
        __syncthreads();
    }
    const float s1max = sred[0];

    if (tid < 32) {
        const int j = j0 + tid;
        const float z  = s2g[j] + s1max;
        const float mi = lrelu_(z);
        Z[j]  = z;
        Ai[j] = __expf(z - mi);
        Bi[j] = __expf(0.01f * z - mi);
        const float d = sb[j] - s1max;
        U[j] = __expf(d);
        W[j] = __expf(0.01f * d);
    }
    {
        const int jl = tid & 31;
        const int part = tid >> 5;          // 0..7
        const float sj = sb[j0 + jl];
        const int jg = j0 + jl;
        int cnt = 0;
        const int k0 = part * (NN / 8);
        #pragma unroll 4
        for (int k = k0; k < k0 + NN / 8; k++) {
            const float sk = sb[k];
            cnt += (sk < sj || (sk == sj && k < jg)) ? 1 : 0;
        }
        atomicAdd(&sRank[jl], cnt);
    }
    __syncthreads();
    if (tid < 32) {
        const int r = sRank[tid];
        iperm[r] = j0 + tid;
        sortedD[r] = sb[j0 + tid] - s1max;
    }
}

// ---------------------------------------------------------------------------
// K3: chunk column sums via iperm gather.
// ---------------------------------------------------------------------------
__global__ __launch_bounds__(256)
void scanA_kernel(const float* __restrict__ last, const float* __restrict__ U,
                  const float* __restrict__ W, const int* __restrict__ iperm,
                  float* __restrict__ chunkSum)
{
    __shared__ int   sj[CH];
    __shared__ float su[CH], sw[CH];
    __shared__ float al[CH][HH], bl[CH][HH];
    const int tid = threadIdx.x;
    const int b   = blockIdx.x;
    if (tid < CH) {
        const int j = iperm[b * CH + tid];
        sj[tid] = j; su[tid] = U[j]; sw[tid] = W[j];
    }
    __syncthreads();
    for (int idx = tid; idx < CH * HH; idx += 256) {
        const int rr = idx >> 6, c = idx & 63;
        const float lv = last[(size_t)sj[rr] * HH + c];
        al[rr][c] = su[rr] * lv;
        bl[rr][c] = sw[rr] * lv;
    }
    __syncthreads();
    if (tid < 130) {
        const int c = tid;
        float s = 0.f;
        if (c < 64) {
            for (int rr = 0; rr < CH; rr++) s += al[rr][c];
        } else if (c < 128) {
            for (int rr = 0; rr < CH; rr++) s += bl[rr][c - 64];
        } else if (c == 128) {
            for (int rr = 0; rr < CH; rr++) s += su[rr];
        } else {
            for (int rr = 0; rr < CH; rr++) s += sw[rr];
        }
        chunkSum[b * RS + c] = s;
    }
}

// ---------------------------------------------------------------------------
// K4: per-column exclusive scan over the 256 chunk sums. One block per column;
// ONE load per thread (full latency parallelism — the fold of this into scanC
// regressed 34 µs in R13 because it became a per-thread serial load chain).
// U-group scans in reversed order = direct suffix, no cancellation.
// ---------------------------------------------------------------------------
__global__ __launch_bounds__(256)
void scanB_kernel(const float* __restrict__ chunkSum, float* __restrict__ chunkOfs)
{
    __shared__ float wt[4];
    const int c   = blockIdx.x;               // 0..129
    const bool rev = (c < 64) || (c == 128);
    const int tid = threadIdx.x;
    const int lane = tid & 63, wv = tid >> 6;
    const int idx = rev ? (NB - 1 - tid) : tid;
    const float orig = chunkSum[idx * RS + c];
    float v = orig;
    #pragma unroll
    for (int d = 1; d < 64; d <<= 1) {
        const float t = __shfl_up(v, d);
        if (lane >= d) v += t;
    }
    if (lane == 63) wt[wv] = v;
    __syncthreads();
    float off = 0.f;
    for (int q = 0; q < wv; q++) off += wt[q];
    chunkOfs[idx * RS + c] = v + off - orig;   // exclusive in scan order
}

// ---------------------------------------------------------------------------
// K5: fill PP rows for this block's 32 ranks (gathered payload in LDS).
// ---------------------------------------------------------------------------
__global__ __launch_bounds__(256)
void scanC_kernel(const float* __restrict__ last, const float* __restrict__ U,
                  const float* __restrict__ W, const int* __restrict__ iperm,
                  const float* __restrict__ chunkOfs, float* __restrict__ PP)
{
    __shared__ int   sj[CH];
    __shared__ float su[CH], sw[CH];
    __shared__ float al[CH][HH], bl[CH][HH];
    const int tid = threadIdx.x;
    const int b   = blockIdx.x;
    if (tid < CH) {
        const int j = iperm[b * CH + tid];
        sj[tid] = j; su[tid] = U[j]; sw[tid] = W[j];
    }
    __syncthreads();
    for (int idx = tid; idx < CH * HH; idx += 256) {
        const int rr = idx >> 6, c = idx & 63;
        const float lv = last[(size_t)sj[rr] * HH + c];
        al[rr][c] = su[rr] * lv;
        bl[rr][c] = sw[rr] * lv;
    }
    __syncthreads();
    if (tid < 130) {
        const int c = tid;
        const bool rev = (c < 64) || (c == 128);
        float run = chunkOfs[b * RS + c];
        if (rev) {
            if (b == NB - 1) PP[(size_t)NN * RS + c] = 0.f;
            for (int rr = CH - 1; rr >= 0; rr--) {
                const float val = (c < 64) ? al[rr][c] : su[rr];
                run += val;
                PP[(size_t)(b * CH + rr) * RS + c] = run;
            }
        } else {
            for (int rr = 0; rr < CH; rr++) {
                PP[(size_t)(b * CH + rr) * RS + c] = run;
                run += (c < 128) ? bl[rr][c - 64] : sw[rr];
            }
            if (b == NB - 1) PP[(size_t)NN * RS + c] = run;
        }
    }
}

// ---------------------------------------------------------------------------
// K6: apply + FC head.
// ---------------------------------------------------------------------------
__global__ __launch_bounds__(256)
void applyfc_kernel(const float* __restrict__ last,
                    const float* __restrict__ Z, const float* __restrict__ Ai, const float* __restrict__ Bi,
                    const float* __restrict__ sortedD, const float* __restrict__ PP,
                    const float* __restrict__ Wfc, const float* __restrict__ bfc,
                    const float* __restrict__ Wout, const float* __restrict__ bout,
                    float* __restrict__ out)
{
    __shared__ float sdD[NN];          // 32 KB
    __shared__ float sW[HH][HH + 1];
    __shared__ float sbF[HH], saF[HH];
    const int tid = threadIdx.x;
    for (int idx = tid; idx < NN; idx += 256) sdD[idx] = sortedD[idx];
    for (int idx = tid; idx < HH * HH; idx += 256) {
        const int h = idx >> 6, d = idx & 63;
        sW[d][h] = Wfc[idx];
    }
    if (tid < HH) { sbF[tid] = bfc[tid]; saF[tid] = Wout[tid]; }
    __syncthreads();

    const int wv = tid >> 6, lane = tid & 63;
    const int i0 = blockIdx.x * 32 + wv * 8;
    float zi[8]; int lo[8], hi[8];
    #pragma unroll
    for (int q = 0; q < 8; q++) { zi[q] = Z[i0 + q]; lo[q] = 0; hi[q] = NN; }
    for (int iter = 0; iter < 13; iter++) {
        #pragma unroll
        for (int q = 0; q < 8; q++) {
            if (lo[q] < hi[q]) {
                const int mid = (lo[q] + hi[q]) >> 1;
                const float dm = sdD[mid];
                if (zi[q] + dm > 0.f) hi[q] = mid; else lo[q] = mid + 1;
            }
        }
    }
    float gv[8];
    #pragma unroll
    for (int q = 0; q < 8; q++) {
        const int i = i0 + q;
        const float* rowp = PP + (size_t)lo[q] * RS;
        const float pu  = rowp[lane];
        const float pw  = rowp[64 + lane];
        const float pud = rowp[128];
        const float pwd = rowp[129];
        const float ai = Ai[i], bi = Bi[i];
        const float numer = bi * pw + ai * pu;
        const float den   = bi * pwd + ai * pud;
        const float lv = last[(size_t)i * HH + lane];
        gv[q] = numer * __builtin_amdgcn_rcpf(den) + lv;
    }
    const float bo = bout[0];
    #pragma unroll
    for (int q = 0; q < 8; q++) {
        float acc = sbF[lane];
        #pragma unroll
        for (int d = 0; d < HH; d++) acc += __shfl(gv[q], d) * sW[d][lane];
        float prod = lrelu_(acc) * saF[lane];
        #pragma unroll
        for (int off = 32; off > 0; off >>= 1) prod += __shfl_xor(prod, off);
        if (lane == 0) out[i0 + q] = prod + bo;
    }
}

extern "C" void kernel_launch(void* const* d_in, const int* in_sizes, int n_in,
                              void* d_out, int out_size, void* d_ws, size_t ws_size,
                              hipStream_t stream)
{
    (void)in_sizes; (void)n_in; (void)out_size; (void)ws_size;
    const float* x    = (const float*)d_in[0];
    const float* Wih0 = (const float*)d_in[1];
    const float* Whh0 = (const float*)d_in[2];
    const float* bih0 = (const float*)d_in[3];
    const float* bhh0 = (const float*)d_in[4];
    const float* Wih1 = (const float*)d_in[5];
    const float* Whh1 = (const float*)d_in[6];
    const float* bih1 = (const float*)d_in[7];
    const float* bhh1 = (const float*)d_in[8];
    const float* Wt   = (const float*)d_in[9];
    const float* bt   = (const float*)d_in[10];
    const float* a    = (const float*)d_in[11];
    const float* Wfc  = (const float*)d_in[12];
    const float* bfc  = (const float*)d_in[13];
    const float* Wout = (const float*)d_in[14];
    const float* bout = (const float*)d_in[15];
    float* out = (float*)d_out;

    float* ws       = (float*)d_ws;
    float* last     = ws;                           // N*H
    float* s1g      = last + (size_t)NN*HH;         // N
    float* s2g      = s1g + NN;                     // N
    float* Z        = s2g + NN;                     // N
    float* Ai       = Z + NN;                       // N
    float* Bi       = Ai + NN;                      // N
    float* U        = Bi + NN;                      // N
    float* W        = U + NN;                       // N
    float* sortedD  = W + NN;                       // N
    int*   iperm    = (int*)(sortedD + NN);         // N ints
    float* chunkSum = (float*)(iperm + NN);         // NB*RS
    float* chunkOfs = chunkSum + NB*RS;             // NB*RS
    float* PP       = chunkOfs + NB*RS;             // (N+1)*RS

    lstm_fused_kernel<<<dim3(NN / 16), dim3(512), 0, stream>>>(
        x, Wih0, Whh0, bih0, bhh0, Wih1, Whh1, bih1, bhh1,
        Wt, bt, a, last, s1g, s2g);
    rankfac_kernel<<<dim3(NB), dim3(256), 0, stream>>>(
        s1g, s2g, Z, Ai, Bi, U, W, iperm, sortedD);
    scanA_kernel<<<dim3(NB), dim3(256), 0, stream>>>(last, U, W, iperm, chunkSum);
    scanB_kernel<<<dim3(130), dim3(256), 0, stream>>>(chunkSum, chunkOfs);
    scanC_kernel<<<dim3(NB), dim3(256), 0, stream>>>(last, U, W, iperm, chunkOfs, PP);
    applyfc_kernel<<<dim3(NB), dim3(256), 0, stream>>>(
        last, Z, Ai, Bi, sortedD, PP, Wfc, bfc, Wout, bout, out);
}